// Round 2
// baseline (63.679 us; speedup 1.0000x reference)
//
#include <hip/hip_runtime.h>
#include <math.h>

// Rational-quadratic spline inverse log-prob (Durkan et al.), inverse pass only.
// Reference returns log(0.5) + where(inside, -logabsdet, 0).
//
// ws float layout (28,832 B total):
//   [0, 1032)        edges : 8 x 129 f32  (cumheights; [.,128] = 1 + 1e-6)
//   [1032, 5160)     pack  : 8 x 129 float4 {h, delta, d0, d1}
//   [5160, 7208)     hint  : 8 x 512 u16 = 8192 B = 2048 floats
//                            (start bin per uniform slot of width 2/512)

#define NB 128
#define NCH 8
#define NSLOT 512
#define WS_EDGES 0
#define WS_PACK  1032
#define WS_HINT  5160
#define TAB_FLOATS 7208   // 5160 + 8*512*2/4

__global__ __launch_bounds__(128) void spline_precompute(
    const float* __restrict__ uw, const float* __restrict__ uh,
    const float* __restrict__ ud, float* __restrict__ ws)
{
    const int c = blockIdx.x;   // channel
    const int i = threadIdx.x;  // bin
    __shared__ float red[128];
    __shared__ float scan[128];
    __shared__ float cum[129];
    __shared__ float wdt[128];
    __shared__ float sdv[129];
    const float DEFAULT_INIT = logf(expf(1.0f - 1e-3f) - 1.0f);

    // ---------------- widths: softmax(uw*10) -> sizes -> cumsum -> knots ----
    float v = uw[c * NB + i] * 10.0f;
    red[i] = v; __syncthreads();
    #pragma unroll
    for (int s = 64; s >= 1; s >>= 1) { if (i < s) red[i] = fmaxf(red[i], red[i + s]); __syncthreads(); }
    float ex = expf(v - red[0]);
    __syncthreads();
    red[i] = ex; __syncthreads();
    #pragma unroll
    for (int s = 64; s >= 1; s >>= 1) { if (i < s) red[i] += red[i + s]; __syncthreads(); }
    float sz = 1e-3f + (1.0f - 1e-3f * NB) * (ex / red[0]);
    __syncthreads();
    scan[i] = sz;
    for (int off = 1; off < NB; off <<= 1) {
        __syncthreads();
        float t = (i >= off) ? scan[i - off] : 0.0f;
        __syncthreads();
        scan[i] += t;
    }
    __syncthreads();
    if (i == 0) cum[0] = -1.0f;
    cum[i + 1] = (i == NB - 1) ? 1.0f : fmaf(2.0f, scan[i], -1.0f);
    __syncthreads();
    wdt[i] = cum[i + 1] - cum[i];
    __syncthreads();   // cum gets reused below

    // ---------------- heights: same pipeline on uh*10 ----------------------
    v = uh[c * NB + i] * 10.0f;
    red[i] = v; __syncthreads();
    #pragma unroll
    for (int s = 64; s >= 1; s >>= 1) { if (i < s) red[i] = fmaxf(red[i], red[i + s]); __syncthreads(); }
    ex = expf(v - red[0]);
    __syncthreads();
    red[i] = ex; __syncthreads();
    #pragma unroll
    for (int s = 64; s >= 1; s >>= 1) { if (i < s) red[i] += red[i + s]; __syncthreads(); }
    sz = 1e-3f + (1.0f - 1e-3f * NB) * (ex / red[0]);
    __syncthreads();
    scan[i] = sz;
    for (int off = 1; off < NB; off <<= 1) {
        __syncthreads();
        float t = (i >= off) ? scan[i - off] : 0.0f;
        __syncthreads();
        scan[i] += t;
    }
    __syncthreads();
    if (i == 0) cum[0] = -1.0f;
    cum[i + 1] = (i == NB - 1) ? 1.0f : fmaf(2.0f, scan[i], -1.0f);

    // ---------------- derivatives: MIN_D + softplus(pad(ud)) ---------------
    float u0 = (i == 0) ? DEFAULT_INIT : ud[c * (NB - 1) + i - 1];
    sdv[i] = 1e-3f + log1pf(expf(u0));
    if (i == NB - 1) sdv[NB] = 1e-3f + log1pf(expf(DEFAULT_INIT));
    __syncthreads();

    // ---------------- emit tables ------------------------------------------
    float* g_edges = ws + WS_EDGES;
    float4* g_pack = reinterpret_cast<float4*>(ws + WS_PACK);
    unsigned short* g_hint = reinterpret_cast<unsigned short*>(ws + WS_HINT);

    float hh = cum[i + 1] - cum[i];
    g_edges[c * 129 + i] = cum[i];
    if (i == NB - 1) g_edges[c * 129 + NB] = 1.0f + 1e-6f;
    g_pack[c * 129 + i] = make_float4(hh, hh / wdt[i], sdv[i], sdv[i + 1]);
    if (i == NB - 1) g_pack[c * 129 + NB] = make_float4(0.0f, 0.0f, 0.0f, 0.0f);

    // hint[s] = max k in [0,127] with cum[k] <= slot_left; guarantees hint <= true bin.
    for (int s = i; s < NSLOT; s += NB) {
        float left = (float)s * (2.0f / NSLOT) - 1.0f;
        int k = 0;
        #pragma unroll
        for (int st = 64; st >= 1; st >>= 1) {   // 64+...+1 = 127, stays in [0,127]
            int t = k + st;
            if (cum[t] <= left) k = t;
        }
        g_hint[c * NSLOT + s] = (unsigned short)k;
    }
}

__global__ __launch_bounds__(256) void spline_main(
    const float4* __restrict__ x4, float4* __restrict__ out4,
    const float* __restrict__ ws, int n4)
{
    __shared__ __align__(16) float tab[TAB_FLOATS];
    {
        float4* dst = reinterpret_cast<float4*>(tab);
        const float4* src = reinterpret_cast<const float4*>(ws);
        for (int t = threadIdx.x; t < TAB_FLOATS / 4; t += 256) dst[t] = src[t];
    }
    __syncthreads();
    const float* se = tab + WS_EDGES;
    const float4* sp = reinterpret_cast<const float4*>(tab + WS_PACK);
    const unsigned short* shint = reinterpret_cast<const unsigned short*>(tab + WS_HINT);

    const float LOG_HALF = -0.6931471805599453f;
    const int stride = gridDim.x * 256;
    for (int i = blockIdx.x * 256 + threadIdx.x; i < n4; i += stride) {
        float4 xv = x4[i];
        float xs[4] = {xv.x, xv.y, xv.z, xv.w};
        float rs[4];
        const int ch0 = (i & 1) * 4;    // flat = 4*i; channel = flat % 8
        #pragma unroll
        for (int j = 0; j < 4; ++j) {
            const int ch = ch0 + j;
            float v = xs[j];
            bool inside = (v >= -1.0f) && (v <= 1.0f);
            float xc = fminf(fmaxf(v, -1.0f), 1.0f);

            // bin search: uniform-slot hint + short linear advance
            int s = (int)((xc + 1.0f) * (NSLOT * 0.5f));
            s = (s > NSLOT - 1) ? NSLOT - 1 : s;
            int k = shint[ch * NSLOT + s];
            k = (k > NB - 1) ? NB - 1 : k;          // safety clamp
            const float* e = se + ch * 129;
            while (k < NB - 1 && e[k + 1] <= xc) ++k;   // bounded; e[128]=1+1e-6 also terminates

            float ich = e[k];
            float4 p = sp[ch * 129 + k];          // {h, delta, d0, d1}
            float ih = p.x, idl = p.y, d0 = p.z, d1 = p.w;

            float dy = xc - ich;
            float t2 = d0 + d1 - 2.0f * idl;
            float aa = dy * t2 + ih * (idl - d0);
            float bb = ih * d0 - dy * t2;
            float cc = -idl * dy;
            float disc = fmaxf(bb * bb - 4.0f * aa * cc, 0.0f);
            float root = __fdividef(2.0f * cc, -bb - sqrtf(disc));
            float th = root * (1.0f - root);
            float den = idl + t2 * th;
            float omr = 1.0f - root;
            float dnum = (idl * idl) * (d1 * root * root + 2.0f * idl * th + d0 * omr * omr);
            float lad = __logf(__fdividef(dnum, den * den));
            rs[j] = inside ? (LOG_HALF - lad) : LOG_HALF;
        }
        out4[i] = make_float4(rs[0], rs[1], rs[2], rs[3]);
    }
}

extern "C" void kernel_launch(void* const* d_in, const int* in_sizes, int n_in,
                              void* d_out, int out_size, void* d_ws, size_t ws_size,
                              hipStream_t stream) {
    const float* x  = (const float*)d_in[0];
    const float* uw = (const float*)d_in[1];
    const float* uh = (const float*)d_in[2];
    const float* ud = (const float*)d_in[3];
    float* ws = (float*)d_ws;

    spline_precompute<<<NCH, NB, 0, stream>>>(uw, uh, ud, ws);

    const int n4 = out_size / 4;   // 16,777,216 / 4
    spline_main<<<2048, 256, 0, stream>>>(
        (const float4*)x, (float4*)d_out, ws, n4);
}

// Round 3
// 54.563 us; speedup vs baseline: 1.1671x; 1.1671x over previous
//
#include <hip/hip_runtime.h>
#include <math.h>

// Rational-quadratic spline inverse log-prob (Durkan et al.), inverse pass only.
// Reference returns log(0.5) + where(inside, -logabsdet, 0).
//
// ws float layout (28,832 B total):
//   [0, 1032)        edges : 8 x 129 f32  (cumheights; [.,128] = 1 + 1e-6)
//   [1032, 5160)     pack  : 8 x 129 float4 {h, delta, d0, d1}
//   [5160, 7208)     hint  : 8 x 1024 u8 = 8192 B
//     slot width 2/1024 = 1.953e-3 < min bin height 2e-3  =>  at most ONE knot
//     per slot => branchless single-step fixup is exact.

#define NB 128
#define NCH 8
#define NSLOT 1024
#define WS_EDGES 0
#define WS_PACK  1032
#define WS_HINT  5160
#define TAB_FLOATS 7208   // 5160 + 8*1024/4

__global__ __launch_bounds__(128) void spline_precompute(
    const float* __restrict__ uw, const float* __restrict__ uh,
    const float* __restrict__ ud, float* __restrict__ ws)
{
    const int c = blockIdx.x;   // channel
    const int i = threadIdx.x;  // bin
    __shared__ float red[128];
    __shared__ float scan[128];
    __shared__ float cum[129];
    __shared__ float wdt[128];
    __shared__ float sdv[129];
    const float DEFAULT_INIT = logf(expf(1.0f - 1e-3f) - 1.0f);

    // ---------------- widths: softmax(uw*10) -> sizes -> cumsum -> knots ----
    float v = uw[c * NB + i] * 10.0f;
    red[i] = v; __syncthreads();
    #pragma unroll
    for (int s = 64; s >= 1; s >>= 1) { if (i < s) red[i] = fmaxf(red[i], red[i + s]); __syncthreads(); }
    float ex = expf(v - red[0]);
    __syncthreads();
    red[i] = ex; __syncthreads();
    #pragma unroll
    for (int s = 64; s >= 1; s >>= 1) { if (i < s) red[i] += red[i + s]; __syncthreads(); }
    float sz = 1e-3f + (1.0f - 1e-3f * NB) * (ex / red[0]);
    __syncthreads();
    scan[i] = sz;
    for (int off = 1; off < NB; off <<= 1) {
        __syncthreads();
        float t = (i >= off) ? scan[i - off] : 0.0f;
        __syncthreads();
        scan[i] += t;
    }
    __syncthreads();
    if (i == 0) cum[0] = -1.0f;
    cum[i + 1] = (i == NB - 1) ? 1.0f : fmaf(2.0f, scan[i], -1.0f);
    __syncthreads();
    wdt[i] = cum[i + 1] - cum[i];
    __syncthreads();   // cum gets reused below

    // ---------------- heights: same pipeline on uh*10 ----------------------
    v = uh[c * NB + i] * 10.0f;
    red[i] = v; __syncthreads();
    #pragma unroll
    for (int s = 64; s >= 1; s >>= 1) { if (i < s) red[i] = fmaxf(red[i], red[i + s]); __syncthreads(); }
    ex = expf(v - red[0]);
    __syncthreads();
    red[i] = ex; __syncthreads();
    #pragma unroll
    for (int s = 64; s >= 1; s >>= 1) { if (i < s) red[i] += red[i + s]; __syncthreads(); }
    sz = 1e-3f + (1.0f - 1e-3f * NB) * (ex / red[0]);
    __syncthreads();
    scan[i] = sz;
    for (int off = 1; off < NB; off <<= 1) {
        __syncthreads();
        float t = (i >= off) ? scan[i - off] : 0.0f;
        __syncthreads();
        scan[i] += t;
    }
    __syncthreads();
    if (i == 0) cum[0] = -1.0f;
    cum[i + 1] = (i == NB - 1) ? 1.0f : fmaf(2.0f, scan[i], -1.0f);

    // ---------------- derivatives: MIN_D + softplus(pad(ud)) ---------------
    float u0 = (i == 0) ? DEFAULT_INIT : ud[c * (NB - 1) + i - 1];
    sdv[i] = 1e-3f + log1pf(expf(u0));
    if (i == NB - 1) sdv[NB] = 1e-3f + log1pf(expf(DEFAULT_INIT));
    __syncthreads();

    // ---------------- emit tables ------------------------------------------
    float* g_edges = ws + WS_EDGES;
    float4* g_pack = reinterpret_cast<float4*>(ws + WS_PACK);
    unsigned char* g_hint = reinterpret_cast<unsigned char*>(ws + WS_HINT);

    float hh = cum[i + 1] - cum[i];
    g_edges[c * 129 + i] = cum[i];
    if (i == NB - 1) g_edges[c * 129 + NB] = 1.0f + 1e-6f;
    g_pack[c * 129 + i] = make_float4(hh, hh / wdt[i], sdv[i], sdv[i + 1]);
    if (i == NB - 1) g_pack[c * 129 + NB] = make_float4(0.0f, 0.0f, 0.0f, 0.0f);

    // hint[s] = max k in [0,127] with cum[k] <= slot_left  (=> true bin in {k, k+1})
    for (int s = i; s < NSLOT; s += NB) {
        float left = (float)s * (2.0f / NSLOT) - 1.0f;
        int k = 0;
        #pragma unroll
        for (int st = 64; st >= 1; st >>= 1) {   // 64+...+1 = 127, stays in [0,127]
            int t = k + st;
            if (cum[t] <= left) k = t;
        }
        g_hint[c * NSLOT + s] = (unsigned char)k;
    }
}

__global__ __launch_bounds__(256) void spline_main(
    const float4* __restrict__ x4, float4* __restrict__ out4,
    const float* __restrict__ ws, int n4)
{
    __shared__ __align__(16) float tab[TAB_FLOATS];
    {
        float4* dst = reinterpret_cast<float4*>(tab);
        const float4* src = reinterpret_cast<const float4*>(ws);
        for (int t = threadIdx.x; t < TAB_FLOATS / 4; t += 256) dst[t] = src[t];
    }
    __syncthreads();

    const float LOG_HALF = -0.6931471805599453f;
    const int stride = gridDim.x * 256;
    for (int i = blockIdx.x * 256 + threadIdx.x; i < n4; i += stride) {
        float4 xv = x4[i];
        float xs[4] = {xv.x, xv.y, xv.z, xv.w};
        float rs[4];
        const int ch0 = (i & 1) * 4;    // flat = 4*i; channel = flat % 8
        // channel-group base pointers; per-j offsets are compile-time immediates
        const float* e = tab + WS_EDGES + ch0 * 129;
        const float4* p4 = reinterpret_cast<const float4*>(tab + WS_PACK) + ch0 * 129;
        const unsigned char* h8 =
            reinterpret_cast<const unsigned char*>(tab + WS_HINT) + ch0 * NSLOT;
        #pragma unroll
        for (int j = 0; j < 4; ++j) {
            float v = xs[j];
            bool inside = (v >= -1.0f) && (v <= 1.0f);
            float xc = fminf(fmaxf(v, -1.0f), 1.0f);

            // slot -> hint -> exact branchless 1-step fixup
            int s = (int)fmaf(xc, (float)(NSLOT / 2), (float)(NSLOT / 2));
            s = (s > NSLOT - 1) ? NSLOT - 1 : s;
            int k = h8[j * NSLOT + s];
            k += (e[j * 129 + k + 1] <= xc) ? 1 : 0;

            float ich = e[j * 129 + k];
            float4 p = p4[j * 129 + k];           // {h, delta, d0, d1}
            float ih = p.x, idl = p.y, d0 = p.z, d1 = p.w;

            float dy = xc - ich;
            float t2 = d0 + d1 - 2.0f * idl;
            float dyt = dy * t2;
            float aa = fmaf(ih, idl - d0, dyt);
            float bb = fmaf(ih, d0, -dyt);
            float cc = -idl * dy;
            float disc = fmaxf(fmaf(bb, bb, -4.0f * aa * cc), 0.0f);
            float root = __fdividef(2.0f * cc, -bb - __builtin_amdgcn_sqrtf(disc));
            float th = root * (1.0f - root);
            float den = fmaf(t2, th, idl);
            float omr = 1.0f - root;
            float inner = fmaf(d1, root * root, fmaf(2.0f * idl, th, d0 * (omr * omr)));
            float dnum = (idl * idl) * inner;
            float lad = __logf(__fdividef(dnum, den * den));
            lad = inside ? lad : 0.0f;
            rs[j] = LOG_HALF - lad;
        }
        out4[i] = make_float4(rs[0], rs[1], rs[2], rs[3]);
    }
}

extern "C" void kernel_launch(void* const* d_in, const int* in_sizes, int n_in,
                              void* d_out, int out_size, void* d_ws, size_t ws_size,
                              hipStream_t stream) {
    const float* x  = (const float*)d_in[0];
    const float* uw = (const float*)d_in[1];
    const float* uh = (const float*)d_in[2];
    const float* ud = (const float*)d_in[3];
    float* ws = (float*)d_ws;

    spline_precompute<<<NCH, NB, 0, stream>>>(uw, uh, ud, ws);

    const int n4 = out_size / 4;   // 16,777,216 / 4
    spline_main<<<2048, 256, 0, stream>>>(
        (const float4*)x, (float4*)d_out, ws, n4);
}

// Round 4
// 49.453 us; speedup vs baseline: 1.2877x; 1.1033x over previous
//
#include <hip/hip_runtime.h>
#include <math.h>

// Rational-quadratic spline inverse log-prob (Durkan et al.), inverse pass only.
// out = log(0.5) - where(inside, logabsdet, 0)
//
// ws float layout (41,216 B total), 8 scalar per-bin arrays of [8ch][129]:
//   a0 @ 0     : ich  = cumheights[k]           (entry 128 = 1+1e-6, for fixup)
//   a1 @ 1032  : T    = d0+d1-2*delta
//   a2 @ 2064  : A    = h*(delta-d0)
//   a3 @ 3096  : B    = h*d0
//   a4 @ 4128  : D    = delta
//   a5 @ 5160  : d0
//   a6 @ 6192  : E    = 2*(delta-d0)
//   a7 @ 7224  : LF2  = 2*log2(delta)
//   hint @ 8256: 8 x 1024 u8 (8192 B). slot width 2/1024 < min bin height 2e-3
//     => at most one knot per slot => branchless 1-step fixup is exact.

#define NB 128
#define NCH 8
#define NSLOT 1024
#define ARR 1032                 // floats per array (8*129)
#define HINT_F 8256              // float offset of hint region
#define TAB_FLOATS 10304         // 8256 + 8192/4

__global__ __launch_bounds__(128) void spline_precompute(
    const float* __restrict__ uw, const float* __restrict__ uh,
    const float* __restrict__ ud, float* __restrict__ ws)
{
    const int c = blockIdx.x;   // channel
    const int i = threadIdx.x;  // bin
    __shared__ float red[128];
    __shared__ float scan[128];
    __shared__ float cum[129];
    __shared__ float wdt[128];
    __shared__ float sdv[129];
    const float DEFAULT_INIT = logf(expf(1.0f - 1e-3f) - 1.0f);

    // ---------------- widths: softmax(uw*10) -> sizes -> cumsum -> knots ----
    float v = uw[c * NB + i] * 10.0f;
    red[i] = v; __syncthreads();
    #pragma unroll
    for (int s = 64; s >= 1; s >>= 1) { if (i < s) red[i] = fmaxf(red[i], red[i + s]); __syncthreads(); }
    float ex = expf(v - red[0]);
    __syncthreads();
    red[i] = ex; __syncthreads();
    #pragma unroll
    for (int s = 64; s >= 1; s >>= 1) { if (i < s) red[i] += red[i + s]; __syncthreads(); }
    float sz = 1e-3f + (1.0f - 1e-3f * NB) * (ex / red[0]);
    __syncthreads();
    scan[i] = sz;
    for (int off = 1; off < NB; off <<= 1) {
        __syncthreads();
        float t = (i >= off) ? scan[i - off] : 0.0f;
        __syncthreads();
        scan[i] += t;
    }
    __syncthreads();
    if (i == 0) cum[0] = -1.0f;
    cum[i + 1] = (i == NB - 1) ? 1.0f : fmaf(2.0f, scan[i], -1.0f);
    __syncthreads();
    wdt[i] = cum[i + 1] - cum[i];
    __syncthreads();   // cum gets reused below

    // ---------------- heights: same pipeline on uh*10 ----------------------
    v = uh[c * NB + i] * 10.0f;
    red[i] = v; __syncthreads();
    #pragma unroll
    for (int s = 64; s >= 1; s >>= 1) { if (i < s) red[i] = fmaxf(red[i], red[i + s]); __syncthreads(); }
    ex = expf(v - red[0]);
    __syncthreads();
    red[i] = ex; __syncthreads();
    #pragma unroll
    for (int s = 64; s >= 1; s >>= 1) { if (i < s) red[i] += red[i + s]; __syncthreads(); }
    sz = 1e-3f + (1.0f - 1e-3f * NB) * (ex / red[0]);
    __syncthreads();
    scan[i] = sz;
    for (int off = 1; off < NB; off <<= 1) {
        __syncthreads();
        float t = (i >= off) ? scan[i - off] : 0.0f;
        __syncthreads();
        scan[i] += t;
    }
    __syncthreads();
    if (i == 0) cum[0] = -1.0f;
    cum[i + 1] = (i == NB - 1) ? 1.0f : fmaf(2.0f, scan[i], -1.0f);

    // ---------------- derivatives: MIN_D + softplus(pad(ud)) ---------------
    float u0 = (i == 0) ? DEFAULT_INIT : ud[c * (NB - 1) + i - 1];
    sdv[i] = 1e-3f + log1pf(expf(u0));
    if (i == NB - 1) sdv[NB] = 1e-3f + log1pf(expf(DEFAULT_INIT));
    __syncthreads();

    // ---------------- emit tables ------------------------------------------
    float hh  = cum[i + 1] - cum[i];
    float idl = hh / wdt[i];
    float d0v = sdv[i], d1v = sdv[i + 1];
    const int o = c * 129 + i;
    ws[o]            = cum[i];
    if (i == NB - 1) ws[c * 129 + NB] = 1.0f + 1e-6f;
    ws[1 * ARR + o] = d0v + d1v - 2.0f * idl;       // T
    ws[2 * ARR + o] = hh * (idl - d0v);             // A
    ws[3 * ARR + o] = hh * d0v;                     // B
    ws[4 * ARR + o] = idl;                          // D
    ws[5 * ARR + o] = d0v;                          // d0
    ws[6 * ARR + o] = 2.0f * (idl - d0v);           // E
    ws[7 * ARR + o] = 2.0f * log2f(idl);            // LF2

    // hint[s] = max k in [0,127] with cum[k] <= slot_left  (true bin = k or k+1)
    unsigned char* g_hint = reinterpret_cast<unsigned char*>(ws + HINT_F);
    for (int s = i; s < NSLOT; s += NB) {
        float left = (float)s * (2.0f / NSLOT) - 1.0f;
        int k = 0;
        #pragma unroll
        for (int st = 64; st >= 1; st >>= 1) {   // 64+...+1 = 127, stays in [0,127]
            int t = k + st;
            if (cum[t] <= left) k = t;
        }
        g_hint[c * NSLOT + s] = (unsigned char)k;
    }
}

__global__ __launch_bounds__(256) void spline_main(
    const float4* __restrict__ x4, float4* __restrict__ out4,
    const float* __restrict__ ws, int npair)
{
    __shared__ __align__(16) float tab[TAB_FLOATS];
    {
        float4* dst = reinterpret_cast<float4*>(tab);
        const float4* src = reinterpret_cast<const float4*>(ws);
        for (int t = threadIdx.x; t < TAB_FLOATS / 4; t += 256) dst[t] = src[t];
    }
    __syncthreads();
    const unsigned char* hint = reinterpret_cast<const unsigned char*>(tab + HINT_F);

    const float LOG_HALF = -0.6931471805599453f;
    const float LN2 = 0.6931471805599453f;
    const int stride = gridDim.x * 256;
    for (int i = blockIdx.x * 256 + threadIdx.x; i < npair; i += stride) {
        float4 xa = x4[2 * i];
        float4 xb = x4[2 * i + 1];
        float xs[8] = {xa.x, xa.y, xa.z, xa.w, xb.x, xb.y, xb.z, xb.w};
        float rs[8];
        #pragma unroll
        for (int j = 0; j < 8; ++j) {           // j == channel (flat % 8)
            float v = xs[j];
            bool inside = __builtin_fabsf(v) <= 1.0f;
            float xc = fminf(fmaxf(v, -1.0f), 1.0f);

            int s = (int)fmaf(xc, (float)(NSLOT / 2), (float)(NSLOT / 2));
            s = (s > NSLOT - 1) ? NSLOT - 1 : s;
            int k = hint[j * NSLOT + s];
            float e1 = tab[j * 129 + k + 1];
            k += (e1 <= xc) ? 1 : 0;

            const float* b = tab + j * 129 + k;   // per-j offsets are imm
            float ich = b[0];
            float T   = b[1 * ARR];
            float A   = b[2 * ARR];
            float B   = b[3 * ARR];
            float D   = b[4 * ARR];
            float d0  = b[5 * ARR];
            float E   = b[6 * ARR];
            float LF2 = b[7 * ARR];

            float dy  = xc - ich;
            float dyt = dy * T;
            float aa  = dyt + A;
            float bb  = B - dyt;
            float cc  = -D * dy;
            float ac  = aa * cc;
            float disc = fmaxf(fmaf(bb, bb, -4.0f * ac), 0.0f);
            float sq   = __builtin_amdgcn_sqrtf(disc);
            float nb   = -bb - sq;
            float root = __fdividef(2.0f * cc, nb);
            float omr  = 1.0f - root;
            float th   = root * omr;
            float den  = fmaf(T, th, D);
            float inner = fmaf(fmaf(T, root, E), root, d0);
            float lad = (__log2f(inner) + LF2 - 2.0f * __log2f(den)) * LN2;
            lad = inside ? lad : 0.0f;
            rs[j] = LOG_HALF - lad;
        }
        out4[2 * i]     = make_float4(rs[0], rs[1], rs[2], rs[3]);
        out4[2 * i + 1] = make_float4(rs[4], rs[5], rs[6], rs[7]);
    }
}

extern "C" void kernel_launch(void* const* d_in, const int* in_sizes, int n_in,
                              void* d_out, int out_size, void* d_ws, size_t ws_size,
                              hipStream_t stream) {
    const float* x  = (const float*)d_in[0];
    const float* uw = (const float*)d_in[1];
    const float* uh = (const float*)d_in[2];
    const float* ud = (const float*)d_in[3];
    float* ws = (float*)d_ws;

    spline_precompute<<<NCH, NB, 0, stream>>>(uw, uh, ud, ws);

    const int npair = out_size / 8;   // 16,777,216 / 8
    spline_main<<<2048, 256, 0, stream>>>(
        (const float4*)x, (float4*)d_out, ws, npair);
}

// Round 5
// 47.286 us; speedup vs baseline: 1.3467x; 1.0458x over previous
//
#include <hip/hip_runtime.h>
#include <math.h>

// Rational-quadratic spline inverse log-prob (Durkan et al.), inverse pass only.
// out = log(0.5) - where(inside, logabsdet, 0)
//
// ws float layout (32,960 B total):
//   EP   @ 0    : 8ch x 129 float2 {e_k, e_{k+1}}   (e_128 = 1+1e-6 sentinel)
//   P4   @ 2064 : 8ch x 129 float4 {h, delta, d0, d1}
//   hint @ 6192 : 8ch x 1024 u8 (8192 B). slot width 2/1024 = 1.953e-3 < min bin
//     height 2e-3 => at most ONE knot per slot => branchless 1-step fixup exact.
// Per element: 3 LDS ops (u8 hint + b64 edge-pair + b128 pack).

#define NB 128
#define NCH 8
#define NSLOT 1024
#define EP_F 0
#define P4_F 2064
#define HINT_F 6192
#define TAB_FLOATS 8240   // 6192 + 8192/4

__global__ __launch_bounds__(128) void spline_precompute(
    const float* __restrict__ uw, const float* __restrict__ uh,
    const float* __restrict__ ud, float* __restrict__ ws)
{
    const int c = blockIdx.x;   // channel
    const int i = threadIdx.x;  // bin
    __shared__ float red[128];
    __shared__ float scan[128];
    __shared__ float cum[129];
    __shared__ float wdt[128];
    __shared__ float sdv[129];
    const float DEFAULT_INIT = logf(expf(1.0f - 1e-3f) - 1.0f);

    // ---------------- widths: softmax(uw*10) -> sizes -> cumsum -> knots ----
    float v = uw[c * NB + i] * 10.0f;
    red[i] = v; __syncthreads();
    #pragma unroll
    for (int s = 64; s >= 1; s >>= 1) { if (i < s) red[i] = fmaxf(red[i], red[i + s]); __syncthreads(); }
    float ex = expf(v - red[0]);
    __syncthreads();
    red[i] = ex; __syncthreads();
    #pragma unroll
    for (int s = 64; s >= 1; s >>= 1) { if (i < s) red[i] += red[i + s]; __syncthreads(); }
    float sz = 1e-3f + (1.0f - 1e-3f * NB) * (ex / red[0]);
    __syncthreads();
    scan[i] = sz;
    for (int off = 1; off < NB; off <<= 1) {
        __syncthreads();
        float t = (i >= off) ? scan[i - off] : 0.0f;
        __syncthreads();
        scan[i] += t;
    }
    __syncthreads();
    if (i == 0) cum[0] = -1.0f;
    cum[i + 1] = (i == NB - 1) ? 1.0f : fmaf(2.0f, scan[i], -1.0f);
    __syncthreads();
    wdt[i] = cum[i + 1] - cum[i];
    __syncthreads();   // cum gets reused below

    // ---------------- heights: same pipeline on uh*10 ----------------------
    v = uh[c * NB + i] * 10.0f;
    red[i] = v; __syncthreads();
    #pragma unroll
    for (int s = 64; s >= 1; s >>= 1) { if (i < s) red[i] = fmaxf(red[i], red[i + s]); __syncthreads(); }
    ex = expf(v - red[0]);
    __syncthreads();
    red[i] = ex; __syncthreads();
    #pragma unroll
    for (int s = 64; s >= 1; s >>= 1) { if (i < s) red[i] += red[i + s]; __syncthreads(); }
    sz = 1e-3f + (1.0f - 1e-3f * NB) * (ex / red[0]);
    __syncthreads();
    scan[i] = sz;
    for (int off = 1; off < NB; off <<= 1) {
        __syncthreads();
        float t = (i >= off) ? scan[i - off] : 0.0f;
        __syncthreads();
        scan[i] += t;
    }
    __syncthreads();
    if (i == 0) cum[0] = -1.0f;
    cum[i + 1] = (i == NB - 1) ? 1.0f : fmaf(2.0f, scan[i], -1.0f);

    // ---------------- derivatives: MIN_D + softplus(pad(ud)) ---------------
    float u0 = (i == 0) ? DEFAULT_INIT : ud[c * (NB - 1) + i - 1];
    sdv[i] = 1e-3f + log1pf(expf(u0));
    if (i == NB - 1) sdv[NB] = 1e-3f + log1pf(expf(DEFAULT_INIT));
    __syncthreads();

    // ---------------- emit tables ------------------------------------------
    float hh  = cum[i + 1] - cum[i];
    float idl = hh / wdt[i];
    const int o = c * 129 + i;
    float2* g_ep = reinterpret_cast<float2*>(ws + EP_F);
    float4* g_p4 = reinterpret_cast<float4*>(ws + P4_F);

    float e1 = (i == NB - 1) ? (1.0f + 1e-6f) : cum[i + 1];
    g_ep[o] = make_float2(cum[i], e1);
    g_p4[o] = make_float4(hh, idl, sdv[i], sdv[i + 1]);
    if (i == NB - 1) {                       // pad entry 128 (never selected)
        g_ep[o + 1] = make_float2(1.0f, 1.0f + 1e-6f);
        g_p4[o + 1] = make_float4(1.0f, 1.0f, 1.0f, 1.0f);
    }

    // hint[s] = max k in [0,127] with cum[k] <= slot_left  (true bin = k or k+1)
    unsigned char* g_hint = reinterpret_cast<unsigned char*>(ws + HINT_F);
    for (int s = i; s < NSLOT; s += NB) {
        float left = (float)s * (2.0f / NSLOT) - 1.0f;
        int k = 0;
        #pragma unroll
        for (int st = 64; st >= 1; st >>= 1) {   // 64+...+1 = 127, stays in [0,127]
            int t = k + st;
            if (cum[t] <= left) k = t;
        }
        g_hint[c * NSLOT + s] = (unsigned char)k;
    }
}

__global__ __launch_bounds__(256) void spline_main(
    const float4* __restrict__ x4, float4* __restrict__ out4,
    const float* __restrict__ ws, int npair)
{
    __shared__ __align__(16) float tab[TAB_FLOATS];
    {
        float4* dst = reinterpret_cast<float4*>(tab);
        const float4* src = reinterpret_cast<const float4*>(ws);
        for (int t = threadIdx.x; t < TAB_FLOATS / 4; t += 256) dst[t] = src[t];
    }
    __syncthreads();
    const float2* ep = reinterpret_cast<const float2*>(tab + EP_F);
    const float4* p4 = reinterpret_cast<const float4*>(tab + P4_F);
    const unsigned char* hint = reinterpret_cast<const unsigned char*>(tab + HINT_F);

    const float LOG_HALF = -0.6931471805599453f;
    const float LN2 = 0.6931471805599453f;
    const int stride = gridDim.x * 256;
    for (int i = blockIdx.x * 256 + threadIdx.x; i < npair; i += stride) {
        float4 xa = x4[2 * i];
        float4 xb = x4[2 * i + 1];
        float xs[8] = {xa.x, xa.y, xa.z, xa.w, xb.x, xb.y, xb.z, xb.w};
        float rs[8];
        #pragma unroll
        for (int j = 0; j < 8; ++j) {           // j == channel (flat % 8)
            float v = xs[j];
            float xc = fminf(fmaxf(v, -1.0f), 1.0f);
            float lmul = (__builtin_fabsf(v) <= 1.0f) ? LN2 : 0.0f;

            int s = (int)fmaf(xc, (float)(NSLOT / 2), (float)(NSLOT / 2));
            s = (s > NSLOT - 1) ? NSLOT - 1 : s;
            int k = hint[j * NSLOT + s];

            float2 ee = ep[j * 129 + k];        // {e_k, e_{k+1}}
            bool adv = (ee.y <= xc);
            int k2 = k + (adv ? 1 : 0);
            float ich = adv ? ee.y : ee.x;

            float4 p = p4[j * 129 + k2];        // {h, delta, d0, d1}
            float h = p.x, dl = p.y, d0 = p.z, d1 = p.w;

            float dy  = xc - ich;
            float T   = fmaf(-2.0f, dl, d0 + d1);
            float dyt = dy * T;
            float B   = h * d0;
            float A   = fmaf(h, dl, -B);        // h*(dl-d0)
            float aa  = dyt + A;
            float bb  = B - dyt;
            float cc  = -dl * dy;
            float m4  = (aa * cc) * -4.0f;
            float disc = fmaxf(fmaf(bb, bb, m4), 0.0f);
            float sq   = __builtin_amdgcn_sqrtf(disc);
            float nb   = -bb - sq;
            float root = __fdividef(cc + cc, nb);
            float omr  = 1.0f - root;
            float th   = root * omr;
            float den  = fmaf(T, th, dl);
            float sdd  = dl - d0;
            float E    = sdd + sdd;
            float inner = fmaf(fmaf(T, root, E), root, d0);
            float q    = __fdividef(dl, den);
            float val  = inner * (q * q);
            rs[j] = fmaf(-lmul, __log2f(val), LOG_HALF);
        }
        out4[2 * i]     = make_float4(rs[0], rs[1], rs[2], rs[3]);
        out4[2 * i + 1] = make_float4(rs[4], rs[5], rs[6], rs[7]);
    }
}

extern "C" void kernel_launch(void* const* d_in, const int* in_sizes, int n_in,
                              void* d_out, int out_size, void* d_ws, size_t ws_size,
                              hipStream_t stream) {
    const float* x  = (const float*)d_in[0];
    const float* uw = (const float*)d_in[1];
    const float* uh = (const float*)d_in[2];
    const float* ud = (const float*)d_in[3];
    float* ws = (float*)d_ws;

    spline_precompute<<<NCH, NB, 0, stream>>>(uw, uh, ud, ws);

    const int npair = out_size / 8;   // 2,097,152
    spline_main<<<1024, 256, 0, stream>>>(
        (const float4*)x, (float4*)d_out, ws, npair);
}

// Round 6
// 44.818 us; speedup vs baseline: 1.4208x; 1.0551x over previous
//
#include <hip/hip_runtime.h>
#include <math.h>

// Rational-quadratic spline inverse log-prob (Durkan et al.), inverse pass only.
// out = log(0.5) - where(inside, logabsdet, 0)
//
// ws float layout (32,960 B total):
//   EP   @ 0    : 8ch x 129 float2 {e_k, e_{k+1}}   (e_128 = 1+1e-6 sentinel)
//   P4   @ 2064 : 8ch x 129 float4 {h, delta, d0, d1}
//   hint @ 6192 : 8ch x 1024 u8 (8192 B). slot width 2/1024 = 1.953e-3 < min bin
//     height 2e-3 => at most ONE knot per slot => branchless 1-step fixup exact.
// Per element: 3 LDS ops (u8 hint -> b64 edge-pair -> b128 pack), issued in
// batched phases of 8 so all chains overlap (needs VGPR headroom: lb(256,4)).

#define NB 128
#define NCH 8
#define NSLOT 1024
#define EP_F 0
#define P4_F 2064
#define HINT_F 6192
#define TAB_FLOATS 8240   // 6192 + 8192/4

__global__ __launch_bounds__(128) void spline_precompute(
    const float* __restrict__ uw, const float* __restrict__ uh,
    const float* __restrict__ ud, float* __restrict__ ws)
{
    const int c = blockIdx.x;   // channel
    const int i = threadIdx.x;  // bin
    __shared__ float red[128];
    __shared__ float scan[128];
    __shared__ float cum[129];
    __shared__ float wdt[128];
    __shared__ float sdv[129];
    const float DEFAULT_INIT = logf(expf(1.0f - 1e-3f) - 1.0f);

    // ---------------- widths: softmax(uw*10) -> sizes -> cumsum -> knots ----
    float v = uw[c * NB + i] * 10.0f;
    red[i] = v; __syncthreads();
    #pragma unroll
    for (int s = 64; s >= 1; s >>= 1) { if (i < s) red[i] = fmaxf(red[i], red[i + s]); __syncthreads(); }
    float ex = expf(v - red[0]);
    __syncthreads();
    red[i] = ex; __syncthreads();
    #pragma unroll
    for (int s = 64; s >= 1; s >>= 1) { if (i < s) red[i] += red[i + s]; __syncthreads(); }
    float sz = 1e-3f + (1.0f - 1e-3f * NB) * (ex / red[0]);
    __syncthreads();
    scan[i] = sz;
    for (int off = 1; off < NB; off <<= 1) {
        __syncthreads();
        float t = (i >= off) ? scan[i - off] : 0.0f;
        __syncthreads();
        scan[i] += t;
    }
    __syncthreads();
    if (i == 0) cum[0] = -1.0f;
    cum[i + 1] = (i == NB - 1) ? 1.0f : fmaf(2.0f, scan[i], -1.0f);
    __syncthreads();
    wdt[i] = cum[i + 1] - cum[i];
    __syncthreads();   // cum gets reused below

    // ---------------- heights: same pipeline on uh*10 ----------------------
    v = uh[c * NB + i] * 10.0f;
    red[i] = v; __syncthreads();
    #pragma unroll
    for (int s = 64; s >= 1; s >>= 1) { if (i < s) red[i] = fmaxf(red[i], red[i + s]); __syncthreads(); }
    ex = expf(v - red[0]);
    __syncthreads();
    red[i] = ex; __syncthreads();
    #pragma unroll
    for (int s = 64; s >= 1; s >>= 1) { if (i < s) red[i] += red[i + s]; __syncthreads(); }
    sz = 1e-3f + (1.0f - 1e-3f * NB) * (ex / red[0]);
    __syncthreads();
    scan[i] = sz;
    for (int off = 1; off < NB; off <<= 1) {
        __syncthreads();
        float t = (i >= off) ? scan[i - off] : 0.0f;
        __syncthreads();
        scan[i] += t;
    }
    __syncthreads();
    if (i == 0) cum[0] = -1.0f;
    cum[i + 1] = (i == NB - 1) ? 1.0f : fmaf(2.0f, scan[i], -1.0f);

    // ---------------- derivatives: MIN_D + softplus(pad(ud)) ---------------
    float u0 = (i == 0) ? DEFAULT_INIT : ud[c * (NB - 1) + i - 1];
    sdv[i] = 1e-3f + log1pf(expf(u0));
    if (i == NB - 1) sdv[NB] = 1e-3f + log1pf(expf(DEFAULT_INIT));
    __syncthreads();

    // ---------------- emit tables ------------------------------------------
    float hh  = cum[i + 1] - cum[i];
    float idl = hh / wdt[i];
    const int o = c * 129 + i;
    float2* g_ep = reinterpret_cast<float2*>(ws + EP_F);
    float4* g_p4 = reinterpret_cast<float4*>(ws + P4_F);

    float e1 = (i == NB - 1) ? (1.0f + 1e-6f) : cum[i + 1];
    g_ep[o] = make_float2(cum[i], e1);
    g_p4[o] = make_float4(hh, idl, sdv[i], sdv[i + 1]);
    if (i == NB - 1) {                       // pad entry 128 (never selected)
        g_ep[o + 1] = make_float2(1.0f, 1.0f + 1e-6f);
        g_p4[o + 1] = make_float4(1.0f, 1.0f, 1.0f, 1.0f);
    }

    // hint[s] = max k in [0,127] with cum[k] <= slot_left  (true bin = k or k+1)
    unsigned char* g_hint = reinterpret_cast<unsigned char*>(ws + HINT_F);
    for (int s = i; s < NSLOT; s += NB) {
        float left = (float)s * (2.0f / NSLOT) - 1.0f;
        int k = 0;
        #pragma unroll
        for (int st = 64; st >= 1; st >>= 1) {   // 64+...+1 = 127, stays in [0,127]
            int t = k + st;
            if (cum[t] <= left) k = t;
        }
        g_hint[c * NSLOT + s] = (unsigned char)k;
    }
}

__global__ __launch_bounds__(256, 4) void spline_main(
    const float4* __restrict__ x4, float4* __restrict__ out4,
    const float* __restrict__ ws, int npair)
{
    __shared__ __align__(16) float tab[TAB_FLOATS];
    {
        float4* dst = reinterpret_cast<float4*>(tab);
        const float4* src = reinterpret_cast<const float4*>(ws);
        for (int t = threadIdx.x; t < TAB_FLOATS / 4; t += 256) dst[t] = src[t];
    }
    __syncthreads();
    const float2* ep = reinterpret_cast<const float2*>(tab + EP_F);
    const float4* p4 = reinterpret_cast<const float4*>(tab + P4_F);
    const unsigned char* hint = reinterpret_cast<const unsigned char*>(tab + HINT_F);

    const float LOG_HALF = -0.6931471805599453f;
    const float LN2 = 0.6931471805599453f;
    const int tid = blockIdx.x * 256 + threadIdx.x;
    const int stride = gridDim.x * 256;

    float4 pfa = x4[2 * tid];
    float4 pfb = x4[2 * tid + 1];

    for (int i = tid; i < npair; i += stride) {
        float4 xa = pfa, xb = pfb;
        int inx = i + stride;
        inx = (inx < npair) ? inx : i;          // safe redundant prefetch on last iter
        pfa = x4[2 * inx];
        pfb = x4[2 * inx + 1];

        float xs[8] = {xa.x, xa.y, xa.z, xa.w, xb.x, xb.y, xb.z, xb.w};

        // ---- phase 1: clamp, slot, hint (8 independent u8 reads) ----------
        float xq[8];
        int kk[8];
        #pragma unroll
        for (int j = 0; j < 8; ++j) {
            float xc = fminf(fmaxf(xs[j], -1.0f), 1.0f);
            xq[j] = xc;
            int s = (int)fmaf(xc, (float)(NSLOT / 2), (float)(NSLOT / 2));
            s = (s > NSLOT - 1) ? NSLOT - 1 : s;
            kk[j] = hint[j * NSLOT + s];
        }

        // ---- phase 2: edge pairs (8 independent b64 reads) ----------------
        float2 ee[8];
        #pragma unroll
        for (int j = 0; j < 8; ++j) ee[j] = ep[j * 129 + kk[j]];

        // ---- phase 3: fixup + pack reads (8 independent b128 reads) -------
        float4 pk[8];
        float dyv[8], lm[8];
        #pragma unroll
        for (int j = 0; j < 8; ++j) {
            bool adv = (ee[j].y <= xq[j]);
            int k2 = kk[j] + (adv ? 1 : 0);
            float ich = adv ? ee[j].y : ee[j].x;
            dyv[j] = xq[j] - ich;
            lm[j] = (xs[j] == xq[j]) ? LN2 : 0.0f;   // inside <=> clamp was a no-op
            pk[j] = p4[j * 129 + k2];
        }

        // ---- phase 4: math ------------------------------------------------
        float rs[8];
        #pragma unroll
        for (int j = 0; j < 8; ++j) {
            float h = pk[j].x, dl = pk[j].y, d0 = pk[j].z, d1 = pk[j].w;
            float dy = dyv[j];

            float T   = fmaf(-2.0f, dl, d0 + d1);
            float dyt = dy * T;
            float B   = h * d0;
            float A   = fmaf(h, dl, -B);            // h*(dl-d0)
            float aa  = dyt + A;
            float bb  = B - dyt;
            float cc  = -dl * dy;
            float ac  = aa * cc;
            float disc = fmaxf(fmaf(-4.0f, ac, bb * bb), 0.0f);
            float sq  = __builtin_amdgcn_sqrtf(disc);
            float w   = -bb - sq;                   // root = u/w, u = 2c
            float u   = cc + cc;
            float w2  = w * w;
            float tu  = T * u;
            float sdd = dl - d0;
            float E   = sdd + sdd;
            float t1  = fmaf(E, w, tu);             // T*u + E*w
            float num = fmaf(t1, u, d0 * w2);       // T*u^2 + E*u*w + d0*w^2
            float d2  = dl * dl;
            float numf = (num * w2) * d2;
            float wmu = w - u;
            float denb = fmaf(tu, wmu, dl * w2);    // dl*w^2 + T*u*(w-u)
            float den2 = denb * denb;
            float val = __fdividef(numf, den2);
            rs[j] = fmaf(-lm[j], __log2f(val), LOG_HALF);
        }

        out4[2 * i]     = make_float4(rs[0], rs[1], rs[2], rs[3]);
        out4[2 * i + 1] = make_float4(rs[4], rs[5], rs[6], rs[7]);
    }
}

extern "C" void kernel_launch(void* const* d_in, const int* in_sizes, int n_in,
                              void* d_out, int out_size, void* d_ws, size_t ws_size,
                              hipStream_t stream) {
    const float* x  = (const float*)d_in[0];
    const float* uw = (const float*)d_in[1];
    const float* uh = (const float*)d_in[2];
    const float* ud = (const float*)d_in[3];
    float* ws = (float*)d_ws;

    spline_precompute<<<NCH, NB, 0, stream>>>(uw, uh, ud, ws);

    const int npair = out_size / 8;   // 2,097,152
    spline_main<<<1024, 256, 0, stream>>>(
        (const float4*)x, (float4*)d_out, ws, npair);
}

// Round 7
// 42.420 us; speedup vs baseline: 1.5012x; 1.0565x over previous
//
#include <hip/hip_runtime.h>
#include <math.h>

// Rational-quadratic spline inverse log-prob (Durkan et al.), inverse pass only.
// out = log(0.5) - where(inside, logabsdet, 0)
//
// ws float layout (28,832 B total):
//   edges @ 0    : 8ch x 129 f32 (cumheights; [.,128] = 1+1e-6 sentinel)
//   P4    @ 1032 : 8ch x 129 float4 {h, delta, d0, d1}
//   hint  @ 5160 : 8ch x 1024 u8 (8192 B). slot width 2/1024 = 1.953e-3 < min
//     bin height 2e-3 => at most ONE knot per slot => 1-step fixup exact.
// Per element: 4 LDS ops (u8 hint -> read2_b32 edges -> b128 pack), batched in
// phases of 8 so chains overlap. Math uses packed f32 (v_pk_*) via float2.

#define NB 128
#define NCH 8
#define NSLOT 1024
#define E_F 0
#define P4_F 1032
#define HINT_F 5160
#define TAB_FLOATS 7208   // 5160 + 8192/4

typedef float v2f __attribute__((ext_vector_type(2)));

__global__ __launch_bounds__(128) void spline_precompute(
    const float* __restrict__ uw, const float* __restrict__ uh,
    const float* __restrict__ ud, float* __restrict__ ws)
{
    const int c = blockIdx.x;   // channel
    const int i = threadIdx.x;  // bin
    __shared__ float red[128];
    __shared__ float scan[128];
    __shared__ float cum[129];
    __shared__ float wdt[128];
    __shared__ float sdv[129];
    const float DEFAULT_INIT = logf(expf(1.0f - 1e-3f) - 1.0f);

    // ---------------- widths: softmax(uw*10) -> sizes -> cumsum -> knots ----
    float v = uw[c * NB + i] * 10.0f;
    red[i] = v; __syncthreads();
    #pragma unroll
    for (int s = 64; s >= 1; s >>= 1) { if (i < s) red[i] = fmaxf(red[i], red[i + s]); __syncthreads(); }
    float ex = expf(v - red[0]);
    __syncthreads();
    red[i] = ex; __syncthreads();
    #pragma unroll
    for (int s = 64; s >= 1; s >>= 1) { if (i < s) red[i] += red[i + s]; __syncthreads(); }
    float sz = 1e-3f + (1.0f - 1e-3f * NB) * (ex / red[0]);
    __syncthreads();
    scan[i] = sz;
    for (int off = 1; off < NB; off <<= 1) {
        __syncthreads();
        float t = (i >= off) ? scan[i - off] : 0.0f;
        __syncthreads();
        scan[i] += t;
    }
    __syncthreads();
    if (i == 0) cum[0] = -1.0f;
    cum[i + 1] = (i == NB - 1) ? 1.0f : fmaf(2.0f, scan[i], -1.0f);
    __syncthreads();
    wdt[i] = cum[i + 1] - cum[i];
    __syncthreads();   // cum gets reused below

    // ---------------- heights: same pipeline on uh*10 ----------------------
    v = uh[c * NB + i] * 10.0f;
    red[i] = v; __syncthreads();
    #pragma unroll
    for (int s = 64; s >= 1; s >>= 1) { if (i < s) red[i] = fmaxf(red[i], red[i + s]); __syncthreads(); }
    ex = expf(v - red[0]);
    __syncthreads();
    red[i] = ex; __syncthreads();
    #pragma unroll
    for (int s = 64; s >= 1; s >>= 1) { if (i < s) red[i] += red[i + s]; __syncthreads(); }
    sz = 1e-3f + (1.0f - 1e-3f * NB) * (ex / red[0]);
    __syncthreads();
    scan[i] = sz;
    for (int off = 1; off < NB; off <<= 1) {
        __syncthreads();
        float t = (i >= off) ? scan[i - off] : 0.0f;
        __syncthreads();
        scan[i] += t;
    }
    __syncthreads();
    if (i == 0) cum[0] = -1.0f;
    cum[i + 1] = (i == NB - 1) ? 1.0f : fmaf(2.0f, scan[i], -1.0f);

    // ---------------- derivatives: MIN_D + softplus(pad(ud)) ---------------
    float u0 = (i == 0) ? DEFAULT_INIT : ud[c * (NB - 1) + i - 1];
    sdv[i] = 1e-3f + log1pf(expf(u0));
    if (i == NB - 1) sdv[NB] = 1e-3f + log1pf(expf(DEFAULT_INIT));
    __syncthreads();

    // ---------------- emit tables ------------------------------------------
    float hh  = cum[i + 1] - cum[i];
    float idl = hh / wdt[i];
    const int o = c * 129 + i;

    ws[E_F + o] = cum[i];
    if (i == NB - 1) ws[E_F + c * 129 + NB] = 1.0f + 1e-6f;   // sentinel
    float4* g_p4 = reinterpret_cast<float4*>(ws + P4_F);
    g_p4[o] = make_float4(hh, idl, sdv[i], sdv[i + 1]);

    // hint[s] = max k in [0,127] with cum[k] <= slot_left  (true bin = k or k+1)
    unsigned char* g_hint = reinterpret_cast<unsigned char*>(ws + HINT_F);
    for (int s = i; s < NSLOT; s += NB) {
        float left = (float)s * (2.0f / NSLOT) - 1.0f;
        int k = 0;
        #pragma unroll
        for (int st = 64; st >= 1; st >>= 1) {   // 64+...+1 = 127, stays in [0,127]
            int t = k + st;
            if (cum[t] <= left) k = t;
        }
        g_hint[c * NSLOT + s] = (unsigned char)k;
    }
}

__global__ __launch_bounds__(256, 4) void spline_main(
    const float4* __restrict__ x4, float4* __restrict__ out4,
    const float* __restrict__ ws, int npair)
{
    __shared__ __align__(16) float tab[TAB_FLOATS];
    {
        float4* dst = reinterpret_cast<float4*>(tab);
        const float4* src = reinterpret_cast<const float4*>(ws);
        for (int t = threadIdx.x; t < TAB_FLOATS / 4; t += 256) dst[t] = src[t];
    }
    __syncthreads();
    const float* eg = tab + E_F;
    const float4* p4 = reinterpret_cast<const float4*>(tab + P4_F);
    const unsigned char* hint = reinterpret_cast<const unsigned char*>(tab + HINT_F);

    const float LOG_HALF = -0.6931471805599453f;
    const float LN2 = 0.6931471805599453f;
    const int tid = blockIdx.x * 256 + threadIdx.x;
    const int stride = gridDim.x * 256;

    float4 pfa, pfb;
    if (tid < npair) { pfa = x4[2 * tid]; pfb = x4[2 * tid + 1]; }

    for (int i = tid; i < npair; i += stride) {
        float4 xa = pfa, xb = pfb;
        int inx = i + stride;
        inx = (inx < npair) ? inx : i;          // safe redundant prefetch on last iter
        pfa = x4[2 * inx];
        pfb = x4[2 * inx + 1];

        float xs[8] = {xa.x, xa.y, xa.z, xa.w, xb.x, xb.y, xb.z, xb.w};

        // ---- phase 1: clamp, slot, hint (8 independent u8 reads) ----------
        float xq[8];
        int kk[8];
        #pragma unroll
        for (int j = 0; j < 8; ++j) {
            float xc = fminf(fmaxf(xs[j], -1.0f), 1.0f);
            xq[j] = xc;
            int s = (int)fmaf(xc, (float)(NSLOT / 2), (float)(NSLOT / 2));
            s = (s > NSLOT - 1) ? NSLOT - 1 : s;
            kk[j] = hint[j * NSLOT + s];
        }

        // ---- phase 2: edge pair reads (read2_b32: e_k, e_{k+1}) -----------
        float e0[8], e1[8];
        #pragma unroll
        for (int j = 0; j < 8; ++j) {
            const float* ej = eg + j * 129 + kk[j];
            e0[j] = ej[0];
            e1[j] = ej[1];
        }

        // ---- phase 3: fixup + pack reads (8 independent b128 reads) -------
        float4 pk[8];
        float dyv[8], lm[8];
        #pragma unroll
        for (int j = 0; j < 8; ++j) {
            bool adv = (e1[j] <= xq[j]);
            int k2 = kk[j] + (adv ? 1 : 0);
            float ich = adv ? e1[j] : e0[j];
            dyv[j] = xq[j] - ich;
            lm[j] = (xs[j] == xq[j]) ? LN2 : 0.0f;   // inside <=> clamp was a no-op
            pk[j] = p4[j * 129 + k2];
        }

        // ---- phase 4: packed-f32 math (v_pk_*), pairs (j, j+4) ------------
        float rs[8];
        #pragma unroll
        for (int jj = 0; jj < 4; ++jj) {
            v2f h  = {pk[jj].x, pk[jj + 4].x};
            v2f dl = {pk[jj].y, pk[jj + 4].y};
            v2f d0 = {pk[jj].z, pk[jj + 4].z};
            v2f d1 = {pk[jj].w, pk[jj + 4].w};
            v2f dy = {dyv[jj],  dyv[jj + 4]};
            const v2f m2 = {-2.0f, -2.0f};
            const v2f m4 = {-4.0f, -4.0f};
            const v2f zz = {0.0f, 0.0f};

            v2f T    = __builtin_elementwise_fma(m2, dl, d0 + d1);
            v2f dyt  = dy * T;
            v2f B    = h * d0;
            v2f A    = __builtin_elementwise_fma(h, dl, -B);   // h*(dl-d0)
            v2f aa   = dyt + A;
            v2f bb   = B - dyt;
            v2f cc   = -dl * dy;
            v2f ac   = aa * cc;
            v2f disc = __builtin_elementwise_max(
                           __builtin_elementwise_fma(m4, ac, bb * bb), zz);
            v2f sq   = {__builtin_amdgcn_sqrtf(disc.x),
                        __builtin_amdgcn_sqrtf(disc.y)};
            v2f w    = -bb - sq;                    // root = u/w, u = 2c
            v2f u    = cc + cc;
            v2f w2   = w * w;
            v2f tu   = T * u;
            v2f sdd  = dl - d0;
            v2f E    = sdd + sdd;
            v2f t1   = __builtin_elementwise_fma(E, w, tu);    // T*u + E*w
            v2f num  = __builtin_elementwise_fma(t1, u, d0 * w2);
            v2f d2   = dl * dl;
            v2f numf = (num * w2) * d2;
            v2f wmu  = w - u;
            v2f denb = __builtin_elementwise_fma(tu, wmu, dl * w2);
            v2f den2 = denb * denb;

            float va = __fdividef(numf.x, den2.x);
            float vb = __fdividef(numf.y, den2.y);
            rs[jj]     = fmaf(-lm[jj],     __log2f(va), LOG_HALF);
            rs[jj + 4] = fmaf(-lm[jj + 4], __log2f(vb), LOG_HALF);
        }

        out4[2 * i]     = make_float4(rs[0], rs[1], rs[2], rs[3]);
        out4[2 * i + 1] = make_float4(rs[4], rs[5], rs[6], rs[7]);
    }
}

extern "C" void kernel_launch(void* const* d_in, const int* in_sizes, int n_in,
                              void* d_out, int out_size, void* d_ws, size_t ws_size,
                              hipStream_t stream) {
    const float* x  = (const float*)d_in[0];
    const float* uw = (const float*)d_in[1];
    const float* uh = (const float*)d_in[2];
    const float* ud = (const float*)d_in[3];
    float* ws = (float*)d_ws;

    spline_precompute<<<NCH, NB, 0, stream>>>(uw, uh, ud, ws);

    const int npair = out_size / 8;   // 2,097,152
    spline_main<<<1280, 256, 0, stream>>>(
        (const float4*)x, (float4*)d_out, ws, npair);
}